// Round 1
// baseline (174.305 us; speedup 1.0000x reference)
//
#include <hip/hip_runtime.h>
#include <hip/hip_bf16.h>
#include <string.h>

#define N 4096
#define D 512
#define MARGIN 0.5f

typedef __attribute__((ext_vector_type(8))) short bf16x8;   // 8 bf16 (4 VGPRs)
typedef __attribute__((ext_vector_type(4))) float f32x4;

__device__ inline float wave_max(float v){
  #pragma unroll
  for (int off=32; off>0; off>>=1) v = fmaxf(v, __shfl_down(v, off, 64));
  return v;
}
__device__ inline float wave_min(float v){
  #pragma unroll
  for (int off=32; off>0; off>>=1) v = fminf(v, __shfl_down(v, off, 64));
  return v;
}
__device__ inline float wave_sum(float v){
  #pragma unroll
  for (int off=32; off>0; off>>=1) v += __shfl_down(v, off, 64);
  return v;
}

// Pass 0: convert X (f32) -> bf16, compute row squared norms.
__global__ __launch_bounds__(128) void prep_kernel(const float* __restrict__ X,
    __hip_bfloat16* __restrict__ Xb, float* __restrict__ sq){
  const int row = blockIdx.x;
  const int t = threadIdx.x;
  const float4 v = *(const float4*)(X + (size_t)row*D + t*4);
  ushort4 s;
  __hip_bfloat16 h;
  h = __float2bfloat16(v.x); memcpy(&s.x, &h, 2);
  h = __float2bfloat16(v.y); memcpy(&s.y, &h, 2);
  h = __float2bfloat16(v.z); memcpy(&s.z, &h, 2);
  h = __float2bfloat16(v.w); memcpy(&s.w, &h, 2);
  *(ushort4*)((unsigned short*)Xb + (size_t)row*D + t*4) = s;
  float ss = v.x*v.x + v.y*v.y + v.z*v.z + v.w*v.w;
  ss = wave_sum(ss);
  __shared__ float red[2];
  if ((t & 63) == 0) red[t >> 6] = ss;
  __syncthreads();
  if (t == 0) sq[row] = red[0] + red[1];
}

// Pass 1: 128x128-tile bf16 MFMA NT-GEMM (C = X X^T), convert to dist, store bf16.
__global__ __launch_bounds__(256,1) void gemm_dist(const __hip_bfloat16* __restrict__ Xb,
    const float* __restrict__ sq, __hip_bfloat16* __restrict__ distb){
  __shared__ __align__(16) __hip_bfloat16 As[128*32];
  __shared__ __align__(16) __hip_bfloat16 Bs[128*32];
  __shared__ float sqi[128];
  __shared__ float sqj[128];
  const int row0 = blockIdx.y * 128, col0 = blockIdx.x * 128;
  const int tid = threadIdx.x;
  const int wave = tid >> 6, lane = tid & 63;
  const int wr = (wave >> 1) * 64, wc = (wave & 1) * 64;
  if (tid < 128) { sqi[tid] = sq[row0 + tid]; sqj[tid] = sq[col0 + tid]; }

  f32x4 acc[4][4];
  #pragma unroll
  for (int a=0;a<4;a++)
    #pragma unroll
    for (int b=0;b<4;b++)
      acc[a][b] = (f32x4){0.f,0.f,0.f,0.f};

  const int srow = lane >> 2;          // 0..15 rows within a 1KB chunk
  const int scol = (lane & 3) * 8;     // 0,8,16,24 (bf16 elems)

  for (int k0 = 0; k0 < D; k0 += 32){
    __syncthreads();   // previous iter's LDS reads done before overwrite
    #pragma unroll
    for (int c=0;c<2;c++){
      const int rbase = (wave*2 + c) * 16;   // wave-uniform
      const __hip_bfloat16* ga = Xb + (size_t)(row0 + rbase + srow)*D + k0 + scol;
      const __hip_bfloat16* gb = Xb + (size_t)(col0 + rbase + srow)*D + k0 + scol;
      __builtin_amdgcn_global_load_lds((const __attribute__((address_space(1))) void*)ga,
          (__attribute__((address_space(3))) void*)(As + rbase*32), 16, 0, 0);
      __builtin_amdgcn_global_load_lds((const __attribute__((address_space(1))) void*)gb,
          (__attribute__((address_space(3))) void*)(Bs + rbase*32), 16, 0, 0);
    }
    __syncthreads();   // compiler drains vmcnt before barrier -> LDS valid

    bf16x8 af[4], bfr[4];
    const int fr = lane & 15, kq = (lane >> 4) * 8;
    #pragma unroll
    for (int a=0;a<4;a++){
      af[a]  = *(const bf16x8*)(As + (wr + a*16 + fr)*32 + kq);
      bfr[a] = *(const bf16x8*)(Bs + (wc + a*16 + fr)*32 + kq);
    }
    #pragma unroll
    for (int a=0;a<4;a++)
      #pragma unroll
      for (int b=0;b<4;b++)
        acc[a][b] = __builtin_amdgcn_mfma_f32_16x16x32_bf16(af[a], bfr[b], acc[a][b], 0, 0, 0);
  }

  // Epilogue: C/D layout col=lane&15, row=(lane>>4)*4+v (m89-verified)
  const int colq = lane & 15, rowq = (lane >> 4) * 4;
  #pragma unroll
  for (int a=0;a<4;a++){
    #pragma unroll
    for (int b=0;b<4;b++){
      const int jloc = wc + b*16 + colq;
      const float sjv = sqj[jloc];
      #pragma unroll
      for (int v=0;v<4;v++){
        const int iloc = wr + a*16 + rowq + v;
        float d2 = sqi[iloc] + sjv - 2.0f * acc[a][b][v];
        float dist = sqrtf(fmaxf(d2, 0.0f) + 1e-12f);
        distb[(size_t)(row0 + iloc) * N + (col0 + jloc)] = __float2bfloat16(dist);
      }
    }
  }
}

// Pass 2: per-row max (max_distance) and hardest-positive.
__global__ __launch_bounds__(256) void rowstats_kernel(const __hip_bfloat16* __restrict__ distb,
    const int* __restrict__ lab, float* __restrict__ rowmax, float* __restrict__ hp){
  const int i = blockIdx.x;
  const int li = lab[i];
  const unsigned int* row = (const unsigned int*)(distb + (size_t)i * N);
  float mall = 0.f, mpos = 0.f;
  for (int j0 = threadIdx.x * 8; j0 < N; j0 += 256*8){
    uint4 pk = *(const uint4*)(row + j0/2);
    unsigned int w[4] = {pk.x, pk.y, pk.z, pk.w};
    #pragma unroll
    for (int q=0;q<4;q++){
      float lo = __uint_as_float(w[q] << 16);
      float hi = __uint_as_float(w[q] & 0xffff0000u);
      int jl = j0 + q*2, jh = jl + 1;
      mall = fmaxf(mall, fmaxf(lo, hi));
      if (lab[jl] == li && jl != i) mpos = fmaxf(mpos, lo);
      if (lab[jh] == li && jh != i) mpos = fmaxf(mpos, hi);
    }
  }
  mall = wave_max(mall); mpos = wave_max(mpos);
  __shared__ float r1[4]; __shared__ float r2[4];
  const int wv = threadIdx.x >> 6, ln = threadIdx.x & 63;
  if (ln == 0){ r1[wv] = mall; r2[wv] = mpos; }
  __syncthreads();
  if (threadIdx.x == 0){
    rowmax[i] = fmaxf(fmaxf(r1[0], r1[1]), fmaxf(r1[2], r1[3]));
    hp[i]     = fmaxf(fmaxf(r2[0], r2[1]), fmaxf(r2[2], r2[3]));
  }
}

// Pass 3: hardest-negative + final scalar loss.
__global__ __launch_bounds__(256) void negpass_kernel(const __hip_bfloat16* __restrict__ distb,
    const int* __restrict__ lab, const float* __restrict__ rowmax, const float* __restrict__ hp,
    float* __restrict__ out){
  const int i = blockIdx.x;
  const int li = lab[i];
  const unsigned int* row = (const unsigned int*)(distb + (size_t)i * N);
  float mn = 3.0e38f;
  for (int j0 = threadIdx.x * 8; j0 < N; j0 += 256*8){
    uint4 pk = *(const uint4*)(row + j0/2);
    unsigned int w[4] = {pk.x, pk.y, pk.z, pk.w};
    #pragma unroll
    for (int q=0;q<4;q++){
      float lo = __uint_as_float(w[q] << 16);
      float hi = __uint_as_float(w[q] & 0xffff0000u);
      int jl = j0 + q*2, jh = jl + 1;
      float al = (jl == i || lab[jl] == li) ? rowmax[jl] : 0.f;
      float ah = (jh == i || lab[jh] == li) ? rowmax[jh] : 0.f;
      mn = fminf(mn, fminf(lo + al, hi + ah));
    }
  }
  mn = wave_min(mn);
  __shared__ float r[4];
  const int wv = threadIdx.x >> 6, ln = threadIdx.x & 63;
  if (ln == 0) r[wv] = mn;
  __syncthreads();
  if (threadIdx.x == 0){
    float hn = fminf(fminf(r[0], r[1]), fminf(r[2], r[3]));
    float contrib = (hp[i] + fmaxf(MARGIN - hn, 0.f)) * (1.0f / (float)N);
    atomicAdd(out, contrib);
  }
}

extern "C" void kernel_launch(void* const* d_in, const int* in_sizes, int n_in,
                              void* d_out, int out_size, void* d_ws, size_t ws_size,
                              hipStream_t stream) {
  (void)in_sizes; (void)n_in; (void)out_size; (void)ws_size;
  const float* X  = (const float*)d_in[0];
  const int* lab  = (const int*)d_in[1];
  float* out      = (float*)d_out;

  char* ws = (char*)d_ws;
  __hip_bfloat16* Xb    = (__hip_bfloat16*)ws;                 // 4 MB
  __hip_bfloat16* distb = Xb + (size_t)N * D;                  // 32 MB
  float* sq     = (float*)(distb + (size_t)N * N);
  float* rowmax = sq + N;
  float* hp     = rowmax + N;

  hipMemsetAsync(d_out, 0, sizeof(float), stream);

  prep_kernel<<<N, 128, 0, stream>>>(X, Xb, sq);
  dim3 grid(N/128, N/128);
  gemm_dist<<<grid, 256, 0, stream>>>(Xb, sq, distb);
  rowstats_kernel<<<N, 256, 0, stream>>>(distb, lab, rowmax, hp);
  negpass_kernel<<<N, 256, 0, stream>>>(distb, lab, rowmax, hp, out);
}

// Round 2
// 164.025 us; speedup vs baseline: 1.0627x; 1.0627x over previous
//
#include <hip/hip_runtime.h>
#include <hip/hip_bf16.h>
#include <string.h>

#define N 4096
#define D 512
#define NUM_CLASSES 64
#define MARGIN 0.5f

typedef __attribute__((ext_vector_type(8))) short bf16x8;   // 8 bf16 (4 VGPRs)
typedef __attribute__((ext_vector_type(4))) float f32x4;

__device__ inline float wave_max(float v){
  #pragma unroll
  for (int off=32; off>0; off>>=1) v = fmaxf(v, __shfl_down(v, off, 64));
  return v;
}
__device__ inline float wave_min(float v){
  #pragma unroll
  for (int off=32; off>0; off>>=1) v = fminf(v, __shfl_down(v, off, 64));
  return v;
}
__device__ inline float wave_sum(float v){
  #pragma unroll
  for (int off=32; off>0; off>>=1) v += __shfl_down(v, off, 64);
  return v;
}

__device__ inline float bflo(unsigned int w){ return __uint_as_float(w << 16); }
__device__ inline float bfhi(unsigned int w){ return __uint_as_float(w & 0xffff0000u); }

// Pass 0: convert X (f32) -> bf16, compute row squared norms.
__global__ __launch_bounds__(128) void prep_kernel(const float* __restrict__ X,
    __hip_bfloat16* __restrict__ Xb, float* __restrict__ sq){
  const int row = blockIdx.x;
  const int t = threadIdx.x;
  const float4 v = *(const float4*)(X + (size_t)row*D + t*4);
  ushort4 s;
  __hip_bfloat16 h;
  h = __float2bfloat16(v.x); memcpy(&s.x, &h, 2);
  h = __float2bfloat16(v.y); memcpy(&s.y, &h, 2);
  h = __float2bfloat16(v.z); memcpy(&s.z, &h, 2);
  h = __float2bfloat16(v.w); memcpy(&s.w, &h, 2);
  *(ushort4*)((unsigned short*)Xb + (size_t)row*D + t*4) = s;
  float ss = v.x*v.x + v.y*v.y + v.z*v.z + v.w*v.w;
  ss = wave_sum(ss);
  __shared__ float red[2];
  if ((t & 63) == 0) red[t >> 6] = ss;
  __syncthreads();
  if (t == 0) sq[row] = red[0] + red[1];
}

// Tiny table: pm[c][j] = (lab[j]==c) ? bf16(1.0) : 0   (0.5 MB, L2-resident)
__global__ __launch_bounds__(256) void maskprep_kernel(const int* __restrict__ lab,
    unsigned short* __restrict__ pm){
  const int j = blockIdx.x * 256 + threadIdx.x;
  const int c = blockIdx.y;
  pm[(size_t)c * N + j] = (lab[j] == c) ? (unsigned short)0x3F80 : (unsigned short)0;
}

// Tiny table: adj[c][j] = (lab[j]==c) ? rowmax[j] : 0   (1 MB, L2-resident)
__global__ __launch_bounds__(256) void adjprep_kernel(const int* __restrict__ lab,
    const float* __restrict__ rowmax, float* __restrict__ adj){
  const int j = blockIdx.x * 256 + threadIdx.x;
  const int c = blockIdx.y;
  adj[(size_t)c * N + j] = (lab[j] == c) ? rowmax[j] : 0.0f;
}

// Pass 1: 128x128-tile bf16 MFMA NT-GEMM (C = X X^T), convert to dist, store bf16.
__global__ __launch_bounds__(256,1) void gemm_dist(const __hip_bfloat16* __restrict__ Xb,
    const float* __restrict__ sq, __hip_bfloat16* __restrict__ distb){
  __shared__ __align__(16) __hip_bfloat16 As[128*32];
  __shared__ __align__(16) __hip_bfloat16 Bs[128*32];
  __shared__ float sqi[128];
  __shared__ float sqj[128];
  const int row0 = blockIdx.y * 128, col0 = blockIdx.x * 128;
  const int tid = threadIdx.x;
  const int wave = tid >> 6, lane = tid & 63;
  const int wr = (wave >> 1) * 64, wc = (wave & 1) * 64;
  if (tid < 128) { sqi[tid] = sq[row0 + tid]; sqj[tid] = sq[col0 + tid]; }

  f32x4 acc[4][4];
  #pragma unroll
  for (int a=0;a<4;a++)
    #pragma unroll
    for (int b=0;b<4;b++)
      acc[a][b] = (f32x4){0.f,0.f,0.f,0.f};

  const int srow = lane >> 2;          // 0..15 rows within a 1KB chunk
  const int scol = (lane & 3) * 8;     // 0,8,16,24 (bf16 elems)

  for (int k0 = 0; k0 < D; k0 += 32){
    __syncthreads();   // previous iter's LDS reads done before overwrite
    #pragma unroll
    for (int c=0;c<2;c++){
      const int rbase = (wave*2 + c) * 16;   // wave-uniform
      const __hip_bfloat16* ga = Xb + (size_t)(row0 + rbase + srow)*D + k0 + scol;
      const __hip_bfloat16* gb = Xb + (size_t)(col0 + rbase + srow)*D + k0 + scol;
      __builtin_amdgcn_global_load_lds((const __attribute__((address_space(1))) void*)ga,
          (__attribute__((address_space(3))) void*)(As + rbase*32), 16, 0, 0);
      __builtin_amdgcn_global_load_lds((const __attribute__((address_space(1))) void*)gb,
          (__attribute__((address_space(3))) void*)(Bs + rbase*32), 16, 0, 0);
    }
    __syncthreads();   // compiler drains vmcnt before barrier -> LDS valid

    bf16x8 af[4], bfr[4];
    const int fr = lane & 15, kq = (lane >> 4) * 8;
    #pragma unroll
    for (int a=0;a<4;a++){
      af[a]  = *(const bf16x8*)(As + (wr + a*16 + fr)*32 + kq);
      bfr[a] = *(const bf16x8*)(Bs + (wc + a*16 + fr)*32 + kq);
    }
    #pragma unroll
    for (int a=0;a<4;a++)
      #pragma unroll
      for (int b=0;b<4;b++)
        acc[a][b] = __builtin_amdgcn_mfma_f32_16x16x32_bf16(af[a], bfr[b], acc[a][b], 0, 0, 0);
  }

  // Epilogue: C/D layout col=lane&15, row=(lane>>4)*4+v (m89-verified)
  const int colq = lane & 15, rowq = (lane >> 4) * 4;
  #pragma unroll
  for (int a=0;a<4;a++){
    #pragma unroll
    for (int b=0;b<4;b++){
      const int jloc = wc + b*16 + colq;
      const float sjv = sqj[jloc];
      #pragma unroll
      for (int v=0;v<4;v++){
        const int iloc = wr + a*16 + rowq + v;
        float d2 = sqi[iloc] + sjv - 2.0f * acc[a][b][v];
        float dist = sqrtf(fmaxf(d2, 0.0f) + 1e-12f);
        distb[(size_t)(row0 + iloc) * N + (col0 + jloc)] = __float2bfloat16(dist);
      }
    }
  }
}

// Pass 2: per-row max (max_distance) and hardest-positive. Branch-free,
// fully coalesced: dist row (uint4) + pm[li] row (uint4), both bf16.
// Diagonal inclusion in mpos is harmless: diag dist <~1 vs hp ~34.
__global__ __launch_bounds__(256) void rowstats_kernel(const __hip_bfloat16* __restrict__ distb,
    const int* __restrict__ lab, const unsigned short* __restrict__ pm,
    float* __restrict__ rowmax, float* __restrict__ hp){
  const int i = blockIdx.x;
  const int li = lab[i];
  const uint4* __restrict__ row  = (const uint4*)(distb + (size_t)i * N);
  const uint4* __restrict__ prow = (const uint4*)(pm + (size_t)li * N);
  float mall = 0.f, mpos = 0.f;
  #pragma unroll
  for (int it = 0; it < 2; ++it){
    const int idx = threadIdx.x + it * 256;     // uint4 index; 8 bf16 each
    const uint4 dk = row[idx];
    const uint4 pk = prow[idx];
    const unsigned int dw[4] = {dk.x, dk.y, dk.z, dk.w};
    const unsigned int pw[4] = {pk.x, pk.y, pk.z, pk.w};
    #pragma unroll
    for (int q=0;q<4;q++){
      float dlo = bflo(dw[q]), dhi = bfhi(dw[q]);
      float plo = bflo(pw[q]), phi = bfhi(pw[q]);
      mall = fmaxf(mall, fmaxf(dlo, dhi));
      mpos = fmaxf(mpos, fmaxf(dlo * plo, dhi * phi));
    }
  }
  mall = wave_max(mall); mpos = wave_max(mpos);
  __shared__ float r1[4]; __shared__ float r2[4];
  const int wv = threadIdx.x >> 6, ln = threadIdx.x & 63;
  if (ln == 0){ r1[wv] = mall; r2[wv] = mpos; }
  __syncthreads();
  if (threadIdx.x == 0){
    rowmax[i] = fmaxf(fmaxf(r1[0], r1[1]), fmaxf(r1[2], r1[3]));
    hp[i]     = fmaxf(fmaxf(r2[0], r2[1]), fmaxf(r2[2], r2[3]));
  }
}

// Pass 3: hardest-negative + final scalar loss. Branch-free, coalesced:
// dist row (uint4 bf16) + adj[li] row (float4). adj covers diag + same-class.
__global__ __launch_bounds__(256) void negpass_kernel(const __hip_bfloat16* __restrict__ distb,
    const int* __restrict__ lab, const float* __restrict__ adj,
    const float* __restrict__ hp, float* __restrict__ out){
  const int i = blockIdx.x;
  const int li = lab[i];
  const uint4*  __restrict__ row  = (const uint4*)(distb + (size_t)i * N);
  const float4* __restrict__ arow = (const float4*)(adj + (size_t)li * N);
  float mn = 3.0e38f;
  #pragma unroll
  for (int it = 0; it < 2; ++it){
    const int idx = threadIdx.x + it * 256;     // uint4 index; 8 bf16 each
    const uint4 dk = row[idx];
    const float4 a0 = arow[idx*2];
    const float4 a1 = arow[idx*2 + 1];
    const unsigned int dw[4] = {dk.x, dk.y, dk.z, dk.w};
    const float av[8] = {a0.x, a0.y, a0.z, a0.w, a1.x, a1.y, a1.z, a1.w};
    #pragma unroll
    for (int q=0;q<4;q++){
      float dlo = bflo(dw[q]), dhi = bfhi(dw[q]);
      mn = fminf(mn, fminf(dlo + av[2*q], dhi + av[2*q+1]));
    }
  }
  mn = wave_min(mn);
  __shared__ float r[4];
  const int wv = threadIdx.x >> 6, ln = threadIdx.x & 63;
  if (ln == 0) r[wv] = mn;
  __syncthreads();
  if (threadIdx.x == 0){
    float hn = fminf(fminf(r[0], r[1]), fminf(r[2], r[3]));
    float contrib = (hp[i] + fmaxf(MARGIN - hn, 0.f)) * (1.0f / (float)N);
    atomicAdd(out, contrib);
  }
}

extern "C" void kernel_launch(void* const* d_in, const int* in_sizes, int n_in,
                              void* d_out, int out_size, void* d_ws, size_t ws_size,
                              hipStream_t stream) {
  (void)in_sizes; (void)n_in; (void)out_size; (void)ws_size;
  const float* X  = (const float*)d_in[0];
  const int* lab  = (const int*)d_in[1];
  float* out      = (float*)d_out;

  char* ws = (char*)d_ws;
  __hip_bfloat16* Xb    = (__hip_bfloat16*)ws;                 // 4 MB
  __hip_bfloat16* distb = Xb + (size_t)N * D;                  // 32 MB
  float* sq     = (float*)(distb + (size_t)N * N);             // 16 KB
  float* rowmax = sq + N;                                      // 16 KB
  float* hp     = rowmax + N;                                  // 16 KB
  unsigned short* pm = (unsigned short*)(hp + N);              // 512 KB
  float* adj    = (float*)(pm + (size_t)NUM_CLASSES * N);      // 1 MB

  hipMemsetAsync(d_out, 0, sizeof(float), stream);

  prep_kernel<<<N, 128, 0, stream>>>(X, Xb, sq);
  maskprep_kernel<<<dim3(N/256, NUM_CLASSES), 256, 0, stream>>>(lab, pm);
  dim3 grid(N/128, N/128);
  gemm_dist<<<grid, 256, 0, stream>>>(Xb, sq, distb);
  rowstats_kernel<<<N, 256, 0, stream>>>(distb, lab, pm, rowmax, hp);
  adjprep_kernel<<<dim3(N/256, NUM_CLASSES), 256, 0, stream>>>(lab, rowmax, adj);
  negpass_kernel<<<N, 256, 0, stream>>>(distb, lab, adj, hp, out);
}

// Round 3
// 121.279 us; speedup vs baseline: 1.4372x; 1.3525x over previous
//
#include <hip/hip_runtime.h>
#include <hip/hip_bf16.h>
#include <string.h>

#define N 4096
#define D 512
#define NUM_CLASSES 64
#define MARGIN 0.5f

typedef __attribute__((ext_vector_type(8))) short bf16x8;   // 8 bf16 (4 VGPRs)
typedef __attribute__((ext_vector_type(4))) float f32x4;

__device__ inline float wave_max(float v){
  #pragma unroll
  for (int off=32; off>0; off>>=1) v = fmaxf(v, __shfl_down(v, off, 64));
  return v;
}
__device__ inline float wave_min(float v){
  #pragma unroll
  for (int off=32; off>0; off>>=1) v = fminf(v, __shfl_down(v, off, 64));
  return v;
}
__device__ inline float wave_sum(float v){
  #pragma unroll
  for (int off=32; off>0; off>>=1) v += __shfl_down(v, off, 64);
  return v;
}

__device__ inline float bflo(unsigned int w){ return __uint_as_float(w << 16); }
__device__ inline float bfhi(unsigned int w){ return __uint_as_float(w & 0xffff0000u); }

// Pass 0: convert X (f32) -> bf16, compute row squared norms.
__global__ __launch_bounds__(128) void prep_kernel(const float* __restrict__ X,
    __hip_bfloat16* __restrict__ Xb, float* __restrict__ sq){
  const int row = blockIdx.x;
  const int t = threadIdx.x;
  const float4 v = *(const float4*)(X + (size_t)row*D + t*4);
  ushort4 s;
  __hip_bfloat16 h;
  h = __float2bfloat16(v.x); memcpy(&s.x, &h, 2);
  h = __float2bfloat16(v.y); memcpy(&s.y, &h, 2);
  h = __float2bfloat16(v.z); memcpy(&s.z, &h, 2);
  h = __float2bfloat16(v.w); memcpy(&s.w, &h, 2);
  *(ushort4*)((unsigned short*)Xb + (size_t)row*D + t*4) = s;
  float ss = v.x*v.x + v.y*v.y + v.z*v.z + v.w*v.w;
  ss = wave_sum(ss);
  __shared__ float red[2];
  if ((t & 63) == 0) red[t >> 6] = ss;
  __syncthreads();
  if (t == 0) sq[row] = red[0] + red[1];
}

// Pass 1: 128x128-tile bf16 MFMA NT-GEMM (C = X X^T) -> dist (bf16 store),
// PLUS fused per-row max / hardest-positive via shuffle + atomicMax.
// rowmax/hp viewed as unsigned (valid order for non-negative floats); must be 0-init.
__global__ __launch_bounds__(256,1) void gemm_dist(const __hip_bfloat16* __restrict__ Xb,
    const float* __restrict__ sq, const int* __restrict__ lab,
    __hip_bfloat16* __restrict__ distb,
    unsigned int* __restrict__ rowmaxu, unsigned int* __restrict__ hpu){
  __shared__ __align__(16) __hip_bfloat16 As[128*32];
  __shared__ __align__(16) __hip_bfloat16 Bs[128*32];
  __shared__ float sqi[128];
  __shared__ float sqj[128];
  __shared__ int labi_s[128];
  __shared__ int labj_s[128];
  const int row0 = blockIdx.y * 128, col0 = blockIdx.x * 128;
  const int tid = threadIdx.x;
  const int wave = tid >> 6, lane = tid & 63;
  const int wr = (wave >> 1) * 64, wc = (wave & 1) * 64;
  if (tid < 128) {
    sqi[tid] = sq[row0 + tid]; sqj[tid] = sq[col0 + tid];
    labi_s[tid] = lab[row0 + tid]; labj_s[tid] = lab[col0 + tid];
  }

  f32x4 acc[4][4];
  #pragma unroll
  for (int a=0;a<4;a++)
    #pragma unroll
    for (int b=0;b<4;b++)
      acc[a][b] = (f32x4){0.f,0.f,0.f,0.f};

  const int srow = lane >> 2;          // 0..15 rows within a 1KB chunk
  const int scol = (lane & 3) * 8;     // 0,8,16,24 (bf16 elems)

  for (int k0 = 0; k0 < D; k0 += 32){
    __syncthreads();   // previous iter's LDS reads done before overwrite
    #pragma unroll
    for (int c=0;c<2;c++){
      const int rbase = (wave*2 + c) * 16;   // wave-uniform
      const __hip_bfloat16* ga = Xb + (size_t)(row0 + rbase + srow)*D + k0 + scol;
      const __hip_bfloat16* gb = Xb + (size_t)(col0 + rbase + srow)*D + k0 + scol;
      __builtin_amdgcn_global_load_lds((const __attribute__((address_space(1))) void*)ga,
          (__attribute__((address_space(3))) void*)(As + rbase*32), 16, 0, 0);
      __builtin_amdgcn_global_load_lds((const __attribute__((address_space(1))) void*)gb,
          (__attribute__((address_space(3))) void*)(Bs + rbase*32), 16, 0, 0);
    }
    __syncthreads();   // compiler drains vmcnt before barrier -> LDS valid

    bf16x8 af[4], bfr[4];
    const int fr = lane & 15, kq = (lane >> 4) * 8;
    #pragma unroll
    for (int a=0;a<4;a++){
      af[a]  = *(const bf16x8*)(As + (wr + a*16 + fr)*32 + kq);
      bfr[a] = *(const bf16x8*)(Bs + (wc + a*16 + fr)*32 + kq);
    }
    #pragma unroll
    for (int a=0;a<4;a++)
      #pragma unroll
      for (int b=0;b<4;b++)
        acc[a][b] = __builtin_amdgcn_mfma_f32_16x16x32_bf16(af[a], bfr[b], acc[a][b], 0, 0, 0);
  }

  // Epilogue: C/D layout col=lane&15, row=(lane>>4)*4+v (m89-verified).
  // Compute dist, store bf16, and track per-(a,v) row max / same-class max.
  const int colq = lane & 15, rowq = (lane >> 4) * 4;
  #pragma unroll
  for (int a=0;a<4;a++){
    float rmax[4] = {0.f,0.f,0.f,0.f};   // per v
    float pmax[4] = {0.f,0.f,0.f,0.f};
    #pragma unroll
    for (int b=0;b<4;b++){
      const int jloc = wc + b*16 + colq;
      const float sjv = sqj[jloc];
      const int jl = labj_s[jloc];
      #pragma unroll
      for (int v=0;v<4;v++){
        const int iloc = wr + a*16 + rowq + v;
        float d2 = sqi[iloc] + sjv - 2.0f * acc[a][b][v];
        float dist = sqrtf(fmaxf(d2, 0.0f) + 1e-12f);
        distb[(size_t)(row0 + iloc) * N + (col0 + jloc)] = __float2bfloat16(dist);
        rmax[v] = fmaxf(rmax[v], dist);
        pmax[v] = fmaxf(pmax[v], (jl == labi_s[iloc]) ? dist : 0.f);
      }
    }
    #pragma unroll
    for (int v=0;v<4;v++){
      float r = rmax[v], p = pmax[v];
      // xor-butterfly over the 16-lane group sharing a row (stays in-group)
      #pragma unroll
      for (int m=1;m<16;m<<=1){
        r = fmaxf(r, __shfl_xor(r, m, 64));
        p = fmaxf(p, __shfl_xor(p, m, 64));
      }
      if (colq == 0){
        const int ig = row0 + wr + a*16 + rowq + v;
        atomicMax(rowmaxu + ig, __float_as_uint(r));
        atomicMax(hpu + ig, __float_as_uint(p));
      }
    }
  }
}

// Tiny table: adj[c][j] = (lab[j]==c) ? rowmax[j] : 0   (1 MB, L2-resident)
__global__ __launch_bounds__(256) void adjprep_kernel(const int* __restrict__ lab,
    const float* __restrict__ rowmax, float* __restrict__ adj){
  const int j = blockIdx.x * 256 + threadIdx.x;
  const int c = blockIdx.y;
  adj[(size_t)c * N + j] = (lab[j] == c) ? rowmax[j] : 0.0f;
}

// Pass 2: hardest-negative + per-row loss (no global atomic).
__global__ __launch_bounds__(256) void negpass_kernel(const __hip_bfloat16* __restrict__ distb,
    const int* __restrict__ lab, const float* __restrict__ adj,
    const float* __restrict__ hp, float* __restrict__ lossvec){
  const int i = blockIdx.x;
  const int li = lab[i];
  const uint4*  __restrict__ row  = (const uint4*)(distb + (size_t)i * N);
  const float4* __restrict__ arow = (const float4*)(adj + (size_t)li * N);
  float mn = 3.0e38f;
  #pragma unroll
  for (int it = 0; it < 2; ++it){
    const int idx = threadIdx.x + it * 256;     // uint4 index; 8 bf16 each
    const uint4 dk = row[idx];
    const float4 a0 = arow[idx*2];
    const float4 a1 = arow[idx*2 + 1];
    const unsigned int dw[4] = {dk.x, dk.y, dk.z, dk.w};
    const float av[8] = {a0.x, a0.y, a0.z, a0.w, a1.x, a1.y, a1.z, a1.w};
    #pragma unroll
    for (int q=0;q<4;q++){
      float dlo = bflo(dw[q]), dhi = bfhi(dw[q]);
      mn = fminf(mn, fminf(dlo + av[2*q], dhi + av[2*q+1]));
    }
  }
  mn = wave_min(mn);
  __shared__ float r[4];
  const int wv = threadIdx.x >> 6, ln = threadIdx.x & 63;
  if (ln == 0) r[wv] = mn;
  __syncthreads();
  if (threadIdx.x == 0){
    float hn = fminf(fminf(r[0], r[1]), fminf(r[2], r[3]));
    lossvec[i] = hp[i] + fmaxf(MARGIN - hn, 0.f);
  }
}

// Pass 3: single-block sum of 4096 per-row losses -> mean -> out[0].
__global__ __launch_bounds__(256) void final_reduce(const float* __restrict__ lossvec,
    float* __restrict__ out){
  const float4* v4 = (const float4*)lossvec;
  float s = 0.f;
  #pragma unroll
  for (int it = 0; it < 4; ++it){
    float4 v = v4[threadIdx.x + it * 256];
    s += v.x + v.y + v.z + v.w;
  }
  s = wave_sum(s);
  __shared__ float r[4];
  if ((threadIdx.x & 63) == 0) r[threadIdx.x >> 6] = s;
  __syncthreads();
  if (threadIdx.x == 0) out[0] = (r[0] + r[1] + r[2] + r[3]) * (1.0f / (float)N);
}

extern "C" void kernel_launch(void* const* d_in, const int* in_sizes, int n_in,
                              void* d_out, int out_size, void* d_ws, size_t ws_size,
                              hipStream_t stream) {
  (void)in_sizes; (void)n_in; (void)out_size; (void)ws_size;
  const float* X  = (const float*)d_in[0];
  const int* lab  = (const int*)d_in[1];
  float* out      = (float*)d_out;

  char* ws = (char*)d_ws;
  __hip_bfloat16* Xb    = (__hip_bfloat16*)ws;                 // 4 MB
  __hip_bfloat16* distb = Xb + (size_t)N * D;                  // 32 MB
  float* sq      = (float*)(distb + (size_t)N * N);            // 16 KB
  float* rowmax  = sq + N;                                     // 16 KB (atomicMax, needs 0-init)
  float* hp      = rowmax + N;                                 // 16 KB (atomicMax, needs 0-init)
  float* lossvec = hp + N;                                     // 16 KB
  float* adj     = lossvec + N;                                // 1 MB

  // rowmax & hp are contiguous -> one async memset (poison 0xAA would win atomicMax)
  hipMemsetAsync(rowmax, 0, 2 * N * sizeof(float), stream);

  prep_kernel<<<N, 128, 0, stream>>>(X, Xb, sq);
  dim3 grid(N/128, N/128);
  gemm_dist<<<grid, 256, 0, stream>>>(Xb, sq, lab, distb,
                                      (unsigned int*)rowmax, (unsigned int*)hp);
  adjprep_kernel<<<dim3(N/256, NUM_CLASSES), 256, 0, stream>>>(lab, rowmax, adj);
  negpass_kernel<<<N, 256, 0, stream>>>(distb, lab, adj, hp, lossvec);
  final_reduce<<<1, 256, 0, stream>>>(lossvec, out);
}

// Round 4
// 94.653 us; speedup vs baseline: 1.8415x; 1.2813x over previous
//
#include <hip/hip_runtime.h>
#include <hip/hip_bf16.h>
#include <string.h>

#define N 4096
#define D 512
#define NB 32            // N/128 tile-rows; triangle blocks = NB*(NB+1)/2 = 528
#define MARGIN 0.5f
#define FINF __builtin_huge_valf()

typedef __attribute__((ext_vector_type(8))) short bf16x8;   // 8 bf16 (4 VGPRs)
typedef __attribute__((ext_vector_type(4))) float f32x4;

__device__ inline float wave_sum(float v){
  #pragma unroll
  for (int off=32; off>0; off>>=1) v += __shfl_down(v, off, 64);
  return v;
}

// Pass 0: X (f32) -> bf16, row squared norms, and init the atomic arrays.
__global__ __launch_bounds__(128) void prep_kernel(const float* __restrict__ X,
    __hip_bfloat16* __restrict__ Xb, float* __restrict__ sq,
    unsigned int* __restrict__ hp2u, unsigned int* __restrict__ nm2u){
  const int row = blockIdx.x;
  const int t = threadIdx.x;
  const float4 v = *(const float4*)(X + (size_t)row*D + t*4);
  ushort4 s;
  __hip_bfloat16 h;
  h = __float2bfloat16(v.x); memcpy(&s.x, &h, 2);
  h = __float2bfloat16(v.y); memcpy(&s.y, &h, 2);
  h = __float2bfloat16(v.z); memcpy(&s.z, &h, 2);
  h = __float2bfloat16(v.w); memcpy(&s.w, &h, 2);
  *(ushort4*)((unsigned short*)Xb + (size_t)row*D + t*4) = s;
  float ss = v.x*v.x + v.y*v.y + v.z*v.z + v.w*v.w;
  ss = wave_sum(ss);
  __shared__ float red[2];
  if ((t & 63) == 0) red[t >> 6] = ss;
  __syncthreads();
  if (t == 0){
    sq[row] = red[0] + red[1];
    hp2u[row] = 0u;                 // max-accumulator (d^2 domain, >= 0)
    nm2u[row] = 0x7F800000u;        // +inf: min-accumulator
  }
}

// Single fused pass: 128x128 bf16 MFMA tiles of X X^T over the UPPER TRIANGLE,
// epilogue reduces hardest-positive (max same-class d2) and hardest-negative
// (min diff-class d2) for both the tile's rows (bi-block) and, via symmetry,
// its columns (bj-block). No dist matrix is ever materialized.
__global__ __launch_bounds__(256,1) void gemm_fused(const __hip_bfloat16* __restrict__ Xb,
    const float* __restrict__ sq, const int* __restrict__ lab,
    unsigned int* __restrict__ hp2u, unsigned int* __restrict__ nm2u){
  __shared__ __align__(16) __hip_bfloat16 As[128*32];
  __shared__ __align__(16) __hip_bfloat16 Bs[128*32];
  __shared__ float sqi[128];
  __shared__ float sqj[128];
  __shared__ int labi_s[128];
  __shared__ int labj_s[128];

  // linear block -> (bi, bj) with bi <= bj
  int rem = blockIdx.x, bi = 0;
  while (rem >= NB - bi){ rem -= NB - bi; bi++; }
  const int bj = bi + rem;
  const int row0 = bi * 128, col0 = bj * 128;

  const int tid = threadIdx.x;
  const int wave = tid >> 6, lane = tid & 63;
  const int wr = (wave >> 1) * 64, wc = (wave & 1) * 64;
  if (tid < 128) {
    sqi[tid] = sq[row0 + tid]; sqj[tid] = sq[col0 + tid];
    labi_s[tid] = lab[row0 + tid]; labj_s[tid] = lab[col0 + tid];
  }

  f32x4 acc[4][4];
  #pragma unroll
  for (int a=0;a<4;a++)
    #pragma unroll
    for (int b=0;b<4;b++)
      acc[a][b] = (f32x4){0.f,0.f,0.f,0.f};

  const int srow = lane >> 2;          // 0..15 rows within a 1KB chunk
  const int scol = (lane & 3) * 8;     // 0,8,16,24 (bf16 elems)

  for (int k0 = 0; k0 < D; k0 += 32){
    __syncthreads();   // previous iter's LDS reads done before overwrite
    #pragma unroll
    for (int c=0;c<2;c++){
      const int rbase = (wave*2 + c) * 16;   // wave-uniform
      const __hip_bfloat16* ga = Xb + (size_t)(row0 + rbase + srow)*D + k0 + scol;
      const __hip_bfloat16* gb = Xb + (size_t)(col0 + rbase + srow)*D + k0 + scol;
      __builtin_amdgcn_global_load_lds((const __attribute__((address_space(1))) void*)ga,
          (__attribute__((address_space(3))) void*)(As + rbase*32), 16, 0, 0);
      __builtin_amdgcn_global_load_lds((const __attribute__((address_space(1))) void*)gb,
          (__attribute__((address_space(3))) void*)(Bs + rbase*32), 16, 0, 0);
    }
    __syncthreads();

    bf16x8 af[4], bfr[4];
    const int fr = lane & 15, kq = (lane >> 4) * 8;
    #pragma unroll
    for (int a=0;a<4;a++){
      af[a]  = *(const bf16x8*)(As + (wr + a*16 + fr)*32 + kq);
      bfr[a] = *(const bf16x8*)(Bs + (wc + a*16 + fr)*32 + kq);
    }
    #pragma unroll
    for (int a=0;a<4;a++)
      #pragma unroll
      for (int b=0;b<4;b++)
        acc[a][b] = __builtin_amdgcn_mfma_f32_16x16x32_bf16(af[a], bfr[b], acc[a][b], 0, 0, 0);
  }

  // Epilogue. C/D layout: col=lane&15, row=(lane>>4)*4+v (m89-verified).
  const int colq = lane & 15, g = lane >> 4, rowq = g * 4;
  int   labi_r[16]; float sqi_r[16];
  #pragma unroll
  for (int a=0;a<4;a++)
    #pragma unroll
    for (int v=0;v<4;v++){
      const int iloc = wr + a*16 + rowq + v;
      labi_r[a*4+v] = labi_s[iloc];
      sqi_r[a*4+v]  = sqi[iloc];
    }

  float pmax_r[16], nmin_r[16];
  #pragma unroll
  for (int k=0;k<16;k++){ pmax_r[k] = 0.f; nmin_r[k] = FINF; }
  float cpos[4], cmin[4];

  #pragma unroll
  for (int b=0;b<4;b++){
    const int jloc = wc + b*16 + colq;
    const float sj = sqj[jloc];
    const int lj = labj_s[jloc];
    float cp = 0.f, cn = FINF;
    #pragma unroll
    for (int a=0;a<4;a++)
      #pragma unroll
      for (int v=0;v<4;v++){
        const int k = a*4+v;
        const float d2 = fmaf(acc[a][b][v], -2.0f, sqi_r[k] + sj);
        const bool same = (labi_r[k] == lj);         // covers diag (i==j)
        const float sp = same ? d2 : 0.0f;           // positive candidate
        const float sn = same ? FINF : d2;           // negative candidate
        pmax_r[k] = fmaxf(pmax_r[k], sp);
        nmin_r[k] = fminf(nmin_r[k], sn);
        cp = fmaxf(cp, sp);
        cn = fminf(cn, sn);
      }
    cpos[b] = cp; cmin[b] = cn;
  }

  // Row-direction: reduce across the 16 lanes sharing a row (xor stays in-group).
  #pragma unroll
  for (int k=0;k<16;k++){
    float p = pmax_r[k], n = nmin_r[k];
    #pragma unroll
    for (int m=1;m<16;m<<=1){
      p = fmaxf(p, __shfl_xor(p, m, 64));
      n = fminf(n, __shfl_xor(n, m, 64));
    }
    if (colq == 0){
      const int ig = row0 + wr + (k>>2)*16 + rowq + (k&3);
      atomicMax(hp2u + ig, __float_as_uint(p));                 // p >= 0
      atomicMin(nm2u + ig, __float_as_uint(fmaxf(n, 0.f)));     // clamp: monotone
    }
  }
  // Column-direction (symmetry): reduce across the 4 lane-groups.
  #pragma unroll
  for (int b=0;b<4;b++){
    float p = cpos[b], n = cmin[b];
    p = fmaxf(p, __shfl_xor(p, 16, 64)); p = fmaxf(p, __shfl_xor(p, 32, 64));
    n = fminf(n, __shfl_xor(n, 16, 64)); n = fminf(n, __shfl_xor(n, 32, 64));
    if (g == 0){
      const int jg = col0 + wc + b*16 + colq;
      atomicMax(hp2u + jg, __float_as_uint(p));
      atomicMin(nm2u + jg, __float_as_uint(fmaxf(n, 0.f)));
    }
  }
}

// Final: loss = mean(sqrt(hp2+eps)) + mean(max(margin - sqrt(nm2+eps), 0))
__global__ __launch_bounds__(256) void final_reduce(const unsigned int* __restrict__ hp2u,
    const unsigned int* __restrict__ nm2u, float* __restrict__ out){
  float s = 0.f;
  #pragma unroll
  for (int it = 0; it < 16; ++it){
    const int i = threadIdx.x + it * 256;
    const float hp2 = __uint_as_float(hp2u[i]);
    const float nm2 = __uint_as_float(nm2u[i]);
    const float hp = sqrtf(hp2 + 1e-12f);
    const float hn = sqrtf(nm2 + 1e-12f);      // +inf if no negatives -> term 0
    s += hp + fmaxf(MARGIN - hn, 0.f);
  }
  s = wave_sum(s);
  __shared__ float r[4];
  if ((threadIdx.x & 63) == 0) r[threadIdx.x >> 6] = s;
  __syncthreads();
  if (threadIdx.x == 0) out[0] = (r[0] + r[1] + r[2] + r[3]) * (1.0f / (float)N);
}

extern "C" void kernel_launch(void* const* d_in, const int* in_sizes, int n_in,
                              void* d_out, int out_size, void* d_ws, size_t ws_size,
                              hipStream_t stream) {
  (void)in_sizes; (void)n_in; (void)out_size; (void)ws_size;
  const float* X  = (const float*)d_in[0];
  const int* lab  = (const int*)d_in[1];
  float* out      = (float*)d_out;

  char* ws = (char*)d_ws;
  __hip_bfloat16* Xb = (__hip_bfloat16*)ws;                    // 4 MB
  float* sq          = (float*)(Xb + (size_t)N * D);           // 16 KB
  unsigned int* hp2u = (unsigned int*)(sq + N);                // 16 KB
  unsigned int* nm2u = hp2u + N;                               // 16 KB

  prep_kernel<<<N, 128, 0, stream>>>(X, Xb, sq, hp2u, nm2u);
  gemm_fused<<<NB*(NB+1)/2, 256, 0, stream>>>(Xb, sq, lab, hp2u, nm2u);
  final_reduce<<<1, 256, 0, stream>>>(hp2u, nm2u, out);
}